// Round 6
// baseline (138.180 us; speedup 1.0000x reference)
//
#include <hip/hip_runtime.h>
#include <stdint.h>

#define DM 1024
#define LS 2048
#define RMS_EPS 1.1920928955078125e-07f
#define S2 0.0029296875f   // BC_SCALE^2 = 3/1024, exact in fp32

typedef __attribute__((ext_vector_type(8))) short bf16x8;
typedef __attribute__((ext_vector_type(4))) float f32x4;
typedef __attribute__((ext_vector_type(2))) unsigned int u32x2;

__device__ __forceinline__ unsigned short f2bf(float f) {
  uint32_t u = __builtin_bit_cast(uint32_t, f);
  u += 0x7FFFu + ((u >> 16) & 1u);   // round-to-nearest-even
  return (unsigned short)(u >> 16);
}

// ---------------------------------------------------------------------------
// K0: pack B (64x1024) and C (64x1024) fp32 -> stacked bf16 [128][1024]
// ---------------------------------------------------------------------------
__global__ __launch_bounds__(256) void k0_prep(const float* __restrict__ B,
                                               const float* __restrict__ C,
                                               unsigned short* __restrict__ Bbf) {
  int i4 = blockIdx.x * 256 + threadIdx.x;          // 0..32767 float4s
  const float4* src = (i4 < 16384) ? (const float4*)B : (const float4*)C;
  float4 v = src[i4 & 16383];
  ushort4 o;
  o.x = f2bf(v.x); o.y = f2bf(v.y); o.z = f2bf(v.z); o.w = f2bf(v.w);
  ((ushort4*)Bbf)[i4] = o;
}

// ---------------------------------------------------------------------------
// KG v6: GEMM + Kw fused; writes ONLY Kw[b][l][16] (512 KB).  BuCuT deleted.
// 512 blocks (b:4 x lt:128, XCD-chunk-swizzled) x 256 thr (4 waves, 3 blk/CU).
// Block: output cols [t0, t0+16), GEMM cols [t0-16, t0+16) (halo recompute,
// 2x MFMA redundancy -- MFMA is <1us of budget).  M=128, N=32, K=1024, BK=64,
// double-buffered LDS, register prefetch (R3-proven 2-sync/step loop).
// No tr-read, no inline asm (R5's absmax 5x growth traced to that path).
// Epilogue: acc -> LDS BuCu (overlays dead At[0]) -> kc-v4-proven Kw
// recurrence (t:16, p:16 threads, shfl-xor reduce over p) -> global Kw.
// ---------------------------------------------------------------------------
__global__ __launch_bounds__(256) void kg(const float* __restrict__ u,
                                          const unsigned short* __restrict__ Bbf,
                                          const float* __restrict__ A,
                                          float* __restrict__ Kwg) {
  const int wg = blockIdx.x;                    // 0..511
  const int sw = (wg & 7) * 64 + (wg >> 3);     // chunked XCD swizzle (bijective)
  const int b  = sw >> 7;
  const int t0 = (sw & 127) * 16;
  const int tid  = threadIdx.x;
  const int lane = tid & 63;
  const int w    = tid >> 6;                    // 0..3
  const int nn = lane & 15, q = lane >> 4;
  const float* ub = u + (size_t)b * DM * LS;

  __shared__ __align__(16) bf16x8 At[2][128][9];   // 36864 B, row pad 9 (even banks)
  __shared__ __align__(16) bf16x8 Ut[2][8][33];    // 8448 B, [k8][l], pad 33
  __shared__ float KwS[16][20];
  float (*BuCu)[132] = (float (*)[132])&At[0][0][0];  // epilogue overlay, 16896 B

  bf16x8 areg[4];
  float4 ureg[4];
  const int ukq = tid >> 3;                     // u-stage: k-quad 0..15 (tid<128)
  const int ulq = tid & 7;                      //          l-quad 0..7
  const int ugc = t0 - 16 + 4*ulq;              // global col (may be <0)

  auto LOAD = [&](int kk) {
    #pragma unroll
    for (int h = 0; h < 4; ++h) {               // A: 1024 chunks, 128B/row segs
      int id = tid + 256*h;
      areg[h] = *(const bf16x8*)(Bbf + (size_t)(id >> 3) * DM + 64*kk + 8*(id & 7));
    }
    if (tid < 128) {                            // u: rows 4*ukq..+4, 16B each
      if (ugc >= 0) {
        #pragma unroll
        for (int r = 0; r < 4; ++r)
          ureg[r] = *(const float4*)(ub + (size_t)(64*kk + 4*ukq + r) * LS + ugc);
      } else {
        #pragma unroll
        for (int r = 0; r < 4; ++r) ureg[r] = make_float4(0.f, 0.f, 0.f, 0.f);
      }
    }
  };
  auto WRITE = [&](int buf) {
    #pragma unroll
    for (int h = 0; h < 4; ++h) {
      int id = tid + 256*h;
      At[buf][id >> 3][id & 7] = areg[h];
    }
    if (tid < 128) {                            // transpose-in-thread: 4k x 4l
      #pragma unroll
      for (int i = 0; i < 4; ++i) {             // half-chunk (4 k) for l=4*ulq+i
        u32x2 pk;
        pk[0] = (unsigned)f2bf(((const float*)&ureg[0])[i]) |
                ((unsigned)f2bf(((const float*)&ureg[1])[i]) << 16);
        pk[1] = (unsigned)f2bf(((const float*)&ureg[2])[i]) |
                ((unsigned)f2bf(((const float*)&ureg[3])[i]) << 16);
        char* dst = (char*)&Ut[buf][ukq >> 1][4*ulq + i] + (ukq & 1) * 8;
        *(u32x2*)dst = pk;
      }
    }
  };

  f32x4 acc[2][2] = {};                         // [rt(M16)][cn(N16)]
  auto COMPUTE = [&](int buf) {
    #pragma unroll
    for (int kc = 0; kc < 2; ++kc) {
      bf16x8 bf0 = Ut[buf][4*kc + q][nn];
      bf16x8 bf1 = Ut[buf][4*kc + q][16 + nn];
      #pragma unroll
      for (int rt = 0; rt < 2; ++rt) {
        bf16x8 af = At[buf][32*w + 16*rt + nn][4*kc + q];
        acc[rt][0] = __builtin_amdgcn_mfma_f32_16x16x32_bf16(af, bf0, acc[rt][0], 0, 0, 0);
        acc[rt][1] = __builtin_amdgcn_mfma_f32_16x16x32_bf16(af, bf1, acc[rt][1], 0, 0, 0);
      }
    }
  };

  LOAD(0); WRITE(0); __syncthreads();
  for (int kk = 0; kk < 16; ++kk) {
    if (kk < 15) LOAD(kk + 1);                  // global loads in flight
    COMPUTE(kk & 1);
    __syncthreads();
    if (kk < 15) { WRITE((kk + 1) & 1); __syncthreads(); }
  }

  // ---- epilogue: acc -> BuCu LDS (At[0] dead: last compute used buf 1) ----
  #pragma unroll
  for (int rt = 0; rt < 2; ++rt)
    #pragma unroll
    for (int cn = 0; cn < 2; ++cn)
      *(f32x4*)&BuCu[16*cn + nn][32*w + 16*rt + 4*q] = acc[rt][cn];
  __syncthreads();

  { // ---- Kw[t][j] = S2 * sum_n Cu[t][n] A^j[n] Bu[t-j][n]  (kc-v4-proven) ----
    const int t = tid >> 4, p = tid & 15;
    const float4 cu = *(const float4*)&BuCu[16 + t][64 + 4*p];
    const float4 aa = *(const float4*)(A + 4*p);
    float pw0 = cu.x * S2, pw1 = cu.y * S2, pw2 = cu.z * S2, pw3 = cu.w * S2;
    #pragma unroll
    for (int j = 0; j < 16; ++j) {
      const float4 b4 = *(const float4*)&BuCu[16 + t - j][4*p];
      float s = pw0*b4.x + pw1*b4.y + pw2*b4.z + pw3*b4.w;
      s += __shfl_xor(s, 1, 64);
      s += __shfl_xor(s, 2, 64);
      s += __shfl_xor(s, 4, 64);
      s += __shfl_xor(s, 8, 64);
      if (p == 0) KwS[t][j] = s;
      pw0 *= aa.x; pw1 *= aa.y; pw2 *= aa.z; pw3 *= aa.w;
    }
  }
  __syncthreads();
  if (tid < 64) {                               // coalesced 1 KB Kw write
    const int t = tid >> 2, jq = tid & 3;
    *(float4*)(Kwg + ((size_t)b * LS + t0 + t) * 16 + 4*jq) =
        *(const float4*)&KwS[t][4*jq];
  }
}

// ---------------------------------------------------------------------------
// KC v5: conv(W=16) + u*D + RMSNorm from u + Kw only (Phase K deleted).
// 512 blocks x 512 thr (2/CU), t-tile 16, ~2 KB LDS.  Kw tile (1 KB) is
// L2-hot on the same XCD (identical grid+swizzle as kg).
// ---------------------------------------------------------------------------
__global__ __launch_bounds__(512) void kc(const float* __restrict__ u,
                                          const float* __restrict__ Kwg,
                                          const float* __restrict__ Dv,
                                          const float* __restrict__ nw,
                                          float* __restrict__ out) {
  const int wg = blockIdx.x;                    // 0..511
  const int sw = (wg & 7) * 64 + (wg >> 3);     // chunked XCD swizzle
  const int b  = sw >> 7;
  const int t0 = (sw & 127) * 16;
  const int tid  = threadIdx.x;
  const int lane = tid & 63;
  const int w    = tid >> 6;
  const float* ub = u + (size_t)b * DM * LS;
  float* ob = out + (size_t)b * DM * LS;

  __shared__ float KwS[16][20];
  __shared__ float SSr[8][16];
  __shared__ float rsqv[16];

  if (tid < 64) {                               // stage Kw tile (1 KB, coalesced)
    const int t = tid >> 2, jq = tid & 3;
    *(float4*)&KwS[t][4*jq] =
        *(const float4*)(Kwg + ((size_t)b * LS + t0 + t) * 16 + 4*jq);
  }
  __syncthreads();

  // ---- conv + u*D, y in registers ----
  const int tg = tid & 3;
  const int dr = tid >> 2;                      // 0..127
  const int cbase = t0 - 16 + 4*tg;
  float y[8][4];
  float ps[4] = {0.f, 0.f, 0.f, 0.f};
  #pragma unroll 1
  for (int c = 0; c < 8; ++c) {
    const int d = dr + 128*c;
    const float* rowp = ub + (size_t)d * LS;
    float wr[20];
    #pragma unroll
    for (int s5 = 0; s5 < 5; ++s5) {
      int g = cbase + 4*s5;
      float4 v = (g >= 0) ? *(const float4*)(rowp + g)
                          : make_float4(0.f, 0.f, 0.f, 0.f);
      wr[4*s5+0] = v.x; wr[4*s5+1] = v.y; wr[4*s5+2] = v.z; wr[4*s5+3] = v.w;
    }
    const float Dd = Dv[d];
    #pragma unroll
    for (int k = 0; k < 4; ++k) {
      f32x4 kv0 = *(const f32x4*)&KwS[4*tg + k][0];   // broadcast b128 reads
      f32x4 kv1 = *(const f32x4*)&KwS[4*tg + k][4];
      f32x4 kv2 = *(const f32x4*)&KwS[4*tg + k][8];
      f32x4 kv3 = *(const f32x4*)&KwS[4*tg + k][12];
      float acc = wr[16 + k] * Dd;                    // skip connection u*D
      #pragma unroll
      for (int j = 0; j < 4; ++j)  acc = fmaf(kv0[j], wr[16 + k - j],      acc);
      #pragma unroll
      for (int j = 0; j < 4; ++j)  acc = fmaf(kv1[j], wr[16 + k - (j+4)],  acc);
      #pragma unroll
      for (int j = 0; j < 4; ++j)  acc = fmaf(kv2[j], wr[16 + k - (j+8)],  acc);
      #pragma unroll
      for (int j = 0; j < 4; ++j)  acc = fmaf(kv3[j], wr[16 + k - (j+12)], acc);
      y[c][k] = acc;
      ps[k] = fmaf(acc, acc, ps[k]);
    }
  }

  // ---- RMS reduce over d ----
  #pragma unroll
  for (int k = 0; k < 4; ++k) {
    ps[k] += __shfl_xor(ps[k], 4, 64);
    ps[k] += __shfl_xor(ps[k], 8, 64);
    ps[k] += __shfl_xor(ps[k], 16, 64);
    ps[k] += __shfl_xor(ps[k], 32, 64);
  }
  if (lane < 4)                                 // lane == tg holds t = 4*lane+k
    *(float4*)&SSr[w][4*lane] = make_float4(ps[0], ps[1], ps[2], ps[3]);
  __syncthreads();
  if (tid < 16) {
    float s = 0.f;
    #pragma unroll
    for (int ww = 0; ww < 8; ++ww) s += SSr[ww][tid];
    rsqv[tid] = rsqrtf(s * (1.f/1024.f) + RMS_EPS);
  }
  __syncthreads();

  // ---- normalize + store ----
  float rq[4];
  #pragma unroll
  for (int k = 0; k < 4; ++k) rq[k] = rsqv[4*tg + k];
  #pragma unroll 1
  for (int c = 0; c < 8; ++c) {
    const int d = dr + 128*c;
    const float wn2 = nw[d];
    float4 o;
    o.x = y[c][0] * rq[0] * wn2;
    o.y = y[c][1] * rq[1] * wn2;
    o.z = y[c][2] * rq[2] * wn2;
    o.w = y[c][3] * rq[3] * wn2;
    *(float4*)(ob + (size_t)d * LS + t0 + 4*tg) = o;
  }
}

// ---------------------------------------------------------------------------
extern "C" void kernel_launch(void* const* d_in, const int* in_sizes, int n_in,
                              void* d_out, int out_size, void* d_ws, size_t ws_size,
                              hipStream_t stream) {
  // inputs: [0]=L(int,1), [1]=u, [2]=A, [3]=B, [4]=C, [5]=D, [6]=norm_w
  const float* u  = (const float*)d_in[1];
  const float* A  = (const float*)d_in[2];
  const float* B  = (const float*)d_in[3];
  const float* C  = (const float*)d_in[4];
  const float* Dv = (const float*)d_in[5];
  const float* nw = (const float*)d_in[6];
  float* out = (float*)d_out;

  float* Kwg = (float*)d_ws;                                         // 512 KB
  unsigned short* Bbf = (unsigned short*)((char*)d_ws + (512u << 10)); // 256 KB

  k0_prep<<<dim3(128), dim3(256), 0, stream>>>(B, C, Bbf);
  kg     <<<dim3(512), dim3(256), 0, stream>>>(u, Bbf, A, Kwg);
  kc     <<<dim3(512), dim3(512), 0, stream>>>(u, Kwg, Dv, nw, out);
}